// Round 1
// baseline (70.593 us; speedup 1.0000x reference)
//
#include <hip/hip_runtime.h>
#include <math.h>

// HierarchicalAttention: softmax_j(score_p[i]+score_c[j]+b) — row-constant
// terms cancel inside the softmax, so out[i,:] = softmax(score_c) @ child for
// every i. |score| <~ 4 so raw expf is fp32-safe: no max-stabilization.
//
// R3 lesson (prev session): grid-wide software barrier costs ~30 us — keep
// two dispatches. THIS ROUND: the 16,640 device-scope atomicAdds into 65
// consecutive floats (256-deep same-address RMW chains through the cross-XCD
// coherence point) are the theorized ~tens-of-us tail. Replaced with a
// per-block partials table (coalesced plain stores, no RMW); K2 redundantly
// reduces the 66.5 KB table per block (L2/L3-resident) before broadcasting.
// Side benefit: d_ws is now fully written before read — no poison semantics.

#define HID   64
#define NB    256     // K1 blocks (C=16384 -> 64 rows each)
#define CHUNK 64
#define PSTR  68      // partial stride in floats (17 float4, keeps 16B align)

__global__ __launch_bounds__(256)
void ha_k1(const float* __restrict__ child,
           const float* __restrict__ attn_w,
           float* __restrict__ part) {   // part[b*PSTR + 0..63]=vec, [64]=esum
    __shared__ float4 s_red[4][16];
    __shared__ float s_es[4];

    const int lane = threadIdx.x & 63;
    const int wave = threadIdx.x >> 6;
    const int fc = (lane & 15) * 4;              // this lane's feature chunk

    const float4 wc4 = *(const float4*)(attn_w + HID + fc);
    const int row0 = blockIdx.x * CHUNK;

    // wave w handles row-quads q = w, w+4, w+8, w+12. One float4 load/lane
    // spans 4 rows: lane l holds features (l&15)*4..+3 of row rowbase+(l>>4).
    float4 acc = make_float4(0.f, 0.f, 0.f, 0.f);
    float esum = 0.f;
    for (int q = wave; q < CHUNK / 4; q += 4) {
        const float4 x = *(const float4*)(child +
                              (size_t)(row0 + q * 4) * HID + lane * 4);
        float p = x.x * wc4.x + x.y * wc4.y + x.z * wc4.z + x.w * wc4.w;
        p += __shfl_xor(p, 1);                   // reduce within 16-lane group
        p += __shfl_xor(p, 2);
        p += __shfl_xor(p, 4);
        p += __shfl_xor(p, 8);                   // p = full row dot
        const float e = expf(p);
        acc.x += e * x.x; acc.y += e * x.y; acc.z += e * x.z; acc.w += e * x.w;
        esum += e;                               // identical across a 16-group
    }
    // fold the 4 row-groups: lanes l, l^16, l^32, l^48 hold the same features
    #pragma unroll
    for (int m = 16; m <= 32; m <<= 1) {
        acc.x += __shfl_xor(acc.x, m);
        acc.y += __shfl_xor(acc.y, m);
        acc.z += __shfl_xor(acc.z, m);
        acc.w += __shfl_xor(acc.w, m);
        esum  += __shfl_xor(esum, m);            // groups hold disjoint rows
    }
    if (lane < 16) s_red[wave][lane] = acc;      // wave's 64-feature partial
    if (lane == 0) s_es[wave] = esum;
    __syncthreads();

    if (wave == 0) {                             // lane = feature 0..63
        const float v = ((const float*)&s_red[0][lane >> 2])[lane & 3]
                      + ((const float*)&s_red[1][lane >> 2])[lane & 3]
                      + ((const float*)&s_red[2][lane >> 2])[lane & 3]
                      + ((const float*)&s_red[3][lane >> 2])[lane & 3];
        part[(size_t)blockIdx.x * PSTR + lane] = v;   // coalesced, no RMW
        if (lane == 0)
            part[(size_t)blockIdx.x * PSTR + HID] =
                s_es[0] + s_es[1] + s_es[2] + s_es[3];
    }
}

__global__ __launch_bounds__(256)
void ha_k2(const float* __restrict__ part, float4* __restrict__ out) {
    __shared__ float4 s_p[4][16];                // per-wave partial fold
    __shared__ float  s_e[4];
    __shared__ float4 s_v4[16];                  // final normalized row

    const int t = threadIdx.x;
    const int lane = t & 63;
    const int wave = t >> 6;
    const int f4 = t & 15;                       // which float4 of 16
    const int ch = t >> 4;                       // b-chunk 0..15 (16 b each)

    // Redundant per-block reduction of the 256x65 partial table (66.5 KB,
    // L2/L3-resident). Lanes with equal ch read consecutive float4s -> each
    // 16-lane group issues one coalesced 256B load per iteration.
    float4 a = make_float4(0.f, 0.f, 0.f, 0.f);
    float es = 0.f;
    #pragma unroll
    for (int j = 0; j < 16; ++j) {
        const int b = ch * 16 + j;
        const float4 p = *(const float4*)(part + (size_t)b * PSTR + f4 * 4);
        a.x += p.x; a.y += p.y; a.z += p.z; a.w += p.w;
        if (f4 == 0)                             // lanes 0,16,32,48 only
            es += part[(size_t)b * PSTR + HID];
    }
    // fold the 4 chunks held within this wave (lanes l, l^16, l^32, l^48
    // share f4 = l&15 and hold disjoint b-chunks)
    #pragma unroll
    for (int m = 16; m <= 32; m <<= 1) {
        a.x += __shfl_xor(a.x, m); a.y += __shfl_xor(a.y, m);
        a.z += __shfl_xor(a.z, m); a.w += __shfl_xor(a.w, m);
        es  += __shfl_xor(es, m);
    }
    if (lane < 16) s_p[wave][lane] = a;          // lane == f4 here
    if (lane == 0) s_e[wave] = es;
    __syncthreads();

    if (t < 16) {                                // fold 4 waves + normalize
        float4 v;
        v.x = s_p[0][t].x + s_p[1][t].x + s_p[2][t].x + s_p[3][t].x;
        v.y = s_p[0][t].y + s_p[1][t].y + s_p[2][t].y + s_p[3][t].y;
        v.z = s_p[0][t].z + s_p[1][t].z + s_p[2][t].z + s_p[3][t].z;
        v.w = s_p[0][t].w + s_p[1][t].w + s_p[2][t].w + s_p[3][t].w;
        const float inv = 1.0f / (s_e[0] + s_e[1] + s_e[2] + s_e[3]);
        v.x *= inv; v.y *= inv; v.z *= inv; v.w *= inv;
        s_v4[t] = v;
    }
    __syncthreads();

    const float4 mine = s_v4[t & 15];            // H=64 -> 16 float4 per row
    const int base = blockIdx.x * 512;           // 32 rows = 512 float4/block
    out[base + t]       = mine;
    out[base + 256 + t] = mine;
}

extern "C" void kernel_launch(void* const* d_in, const int* in_sizes, int n_in,
                              void* d_out, int out_size, void* d_ws, size_t ws_size,
                              hipStream_t stream) {
    const float* child  = (const float*)d_in[1];   // (16384, 64)
    const float* attn_w = (const float*)d_in[2];   // (1, 128)

    float* part = (float*)d_ws;                    // NB*PSTR floats = 68 KB

    ha_k1<<<NB, 256, 0, stream>>>(child, attn_w, part);
    ha_k2<<<NB, 256, 0, stream>>>(part, (float4*)d_out);
}